// Round 11
// baseline (1458.909 us; speedup 1.0000x reference)
//
#include <hip/hip_runtime.h>
#include <math.h>

// ---------------------------------------------------------------------------
// AnticipatoryRestaurantGNN round 11:
//  - k_qkvs: back to R9's 128x128 tile / 32KB LDS structure (R10's A-resident
//    64-row variant was occupancy+barrier bound: 67.5KB LDS -> 2 blocks/CU,
//    HBM 0.97 TB/s).  Keeps R10's wins: split K/V planes (no RMW write
//    amplification) and BN+LeakyReLU fused into the A-staging (register
//    load + transform + ds_write; B still global_load_lds width=16).
//  - per-layer bnapply eliminated (bnscale -> fused into next qkvs; final
//    apply once before pooling).
// ---------------------------------------------------------------------------

#define EPS 1e-5f
typedef unsigned short ushort_t;
typedef unsigned int uint_t;

using f32x4 = __attribute__((ext_vector_type(4))) float;
using s16x8 = __attribute__((ext_vector_type(8))) short;
using u16x8 = __attribute__((ext_vector_type(8))) unsigned short;

__device__ __forceinline__ ushort_t f2bf(float f) {
  union { float f; uint_t u; } v; v.f = f;
  uint_t u = v.u;
  uint_t r = (u + 0x7FFFu + ((u >> 16) & 1u)) >> 16;   // RNE
  return (ushort_t)r;
}
__device__ __forceinline__ float bf2f(ushort_t h) {
  union { uint_t u; float f; } v; v.u = ((uint_t)h) << 16;
  return v.f;
}

__device__ __forceinline__ void gl_lds16(const void* g, void* l) {
  __builtin_amdgcn_global_load_lds(
      (const __attribute__((address_space(1))) void*)g,
      (__attribute__((address_space(3))) void*)l, 16, 0, 0);
}

// DPP rotate-add reduction over each 16-lane row (per-head), pure VALU.
template <int CTRL>
__device__ __forceinline__ float dpp_add(float x) {
  int v = __builtin_amdgcn_update_dpp(0, __float_as_int(x), CTRL, 0xF, 0xF, true);
  return x + __int_as_float(v);
}
__device__ __forceinline__ float red16_dpp(float x) {
  x = dpp_add<0x121>(x);   // row_ror:1
  x = dpp_add<0x122>(x);   // row_ror:2
  x = dpp_add<0x124>(x);   // row_ror:4
  x = dpp_add<0x128>(x);   // row_ror:8
  return x;
}

// ---------------- CSR build (by dst; dst reused across all 4 layers) -------
__global__ void k_count(const int* __restrict__ dst, int* __restrict__ deg, int n) {
  int i = blockIdx.x * 256 + threadIdx.x;
  if (i < n) atomicAdd(&deg[dst[i]], 1);
}

__global__ void k_scan(const int* __restrict__ deg, int* __restrict__ row_ptr, int n) {
  __shared__ int wsum[16];
  __shared__ int carry_s;
  int t = threadIdx.x, lane = t & 63, w = t >> 6;
  if (t == 0) { carry_s = 0; row_ptr[0] = 0; }
  __syncthreads();
  for (int base = 0; base < n; base += 1024) {
    int v = (base + t < n) ? deg[base + t] : 0;
    int x = v;
#pragma unroll
    for (int off = 1; off < 64; off <<= 1) {
      int y = __shfl_up(x, off, 64);
      if (lane >= off) x += y;
    }
    if (lane == 63) wsum[w] = x;
    __syncthreads();
    if (w == 0 && lane < 16) {
      int s = wsum[lane];
#pragma unroll
      for (int off = 1; off < 16; off <<= 1) {
        int y = __shfl_up(s, off, 64);
        if (lane >= off) s += y;
      }
      wsum[lane] = s;
    }
    __syncthreads();
    int add = (w > 0) ? wsum[w - 1] : 0;
    int incl = x + add + carry_s;
    if (base + t < n) row_ptr[base + t + 1] = incl;
    __syncthreads();
    if (t == 1023) carry_s = incl;
    __syncthreads();
  }
}

__global__ void k_scatter(const int* __restrict__ dst, const int* __restrict__ row_ptr,
                          int* __restrict__ fill, int* __restrict__ csr, int n) {
  int i = blockIdx.x * 256 + threadIdx.x;
  if (i < n) {
    int d = dst[i];
    int pos = atomicAdd(&fill[d], 1);
    csr[row_ptr[d] + pos] = i;
  }
}

// ---------------- weight convert: Wcat_t[l][n=1152][k=256] bf16 ------------
__global__ void k_wconv(const float* __restrict__ Wq, const float* __restrict__ Wk,
                        const float* __restrict__ Wv, const float* __restrict__ Ws,
                        ushort_t* __restrict__ Wcat_t) {
  __shared__ float tile[32][33];
  int l = blockIdx.z >> 2, sel = blockIdx.z & 3;
  const float* W = (sel == 0) ? Wq : (sel == 1) ? Wk : (sel == 2) ? Wv : Ws;
  W += (size_t)l * 65536;
  int k0 = blockIdx.x * 32, n0 = blockIdx.y * 32;
  int tx = threadIdx.x, ty = threadIdx.y;           // 32 x 8
#pragma unroll
  for (int i = 0; i < 32; i += 8) tile[ty + i][tx] = W[(size_t)(k0 + ty + i) * 256 + n0 + tx];
  __syncthreads();
  ushort_t* dst = Wcat_t + (size_t)l * (1152 * 256) + (size_t)(sel * 256 + n0) * 256 + k0;
#pragma unroll
  for (int i = 0; i < 32; i += 8) dst[(size_t)(ty + i) * 256 + tx] = f2bf(tile[tx][ty + i]);
}

// composite rows 1024..1091: M[ci][j] = sum_{c in head(j)} Wq[ci][c]*w2[c]
__global__ void k_mkdq(const float* __restrict__ Wq, const float* __restrict__ bq,
                       const float* __restrict__ We, const float* __restrict__ be,
                       ushort_t* __restrict__ Wcat_t, float* __restrict__ bias_cat) {
  int j = blockIdx.x;        // 0..67
  int l = blockIdx.y;        // 0..3
  int ci = threadIdx.x;      // 0..255
  __shared__ float w2[64];
  int h = (j < 64) ? (j >> 4) : (j - 64);
  if (ci < 64) {
    float v;
    if (j < 64) v = We[(size_t)l * 4096 + (j & 15) * 256 + h * 64 + ci];
    else        v = be[l * 256 + h * 64 + ci];
    w2[ci] = v * 0.125f;
  }
  __syncthreads();
  const float* Wq_l = Wq + (size_t)l * 65536;
  float acc = 0.f;
#pragma unroll 8
  for (int c = 0; c < 64; ++c) acc += Wq_l[(size_t)ci * 256 + h * 64 + c] * w2[c];
  Wcat_t[(size_t)l * (1152 * 256) + (size_t)(1024 + j) * 256 + ci] = f2bf(acc);
  if (ci == 0) {
    const float* bq_l = bq + l * 256;
    float d0 = 0.f;
    for (int c = 0; c < 64; ++c) d0 += bq_l[h * 64 + c] * w2[c];
    bias_cat[l * 1152 + 1024 + j] = d0;
  }
}

__global__ void k_bconv(const float* __restrict__ bq, const float* __restrict__ bk,
                        const float* __restrict__ bv, const float* __restrict__ bs,
                        float* __restrict__ bias_cat) {
  int idx = blockIdx.x * 256 + threadIdx.x;   // 4096 total
  if (idx >= 4096) return;
  int l = idx >> 10, rest = idx & 1023, sel = rest >> 8, c = rest & 255;
  const float* p = (sel == 0) ? bq : (sel == 1) ? bk : (sel == 2) ? bv : bs;
  bias_cat[l * 1152 + rest] = p[l * 256 + c];
}

// ---------------- fp32 tiled GEMM (input projection only, bf16 out) --------
#define BM 128
#define BN 64
#define BK 16
__global__ __launch_bounds__(256) void k_gemm(
    const float* __restrict__ A, const float* __restrict__ B,
    const float* __restrict__ bias, ushort_t* __restrict__ C16,
    int M, int Kd, int Nd) {
  __shared__ float As[BK][BM + 4];
  __shared__ float Bs[BK][BN + 4];
  int t = threadIdx.x;
  int tx = t & 15, ty = t >> 4;
  int row0 = blockIdx.y * BM, col0 = blockIdx.x * BN;
  float acc[8][4] = {};
  for (int k0 = 0; k0 < Kd; k0 += BK) {
#pragma unroll
    for (int i = 0; i < 2; ++i) {
      int idx = t + i * 256;
      int r = idx >> 2, kk = (idx & 3) * 4;
      float4 a = make_float4(0.f, 0.f, 0.f, 0.f);
      if (row0 + r < M) a = *(const float4*)(A + (size_t)(row0 + r) * Kd + k0 + kk);
      As[kk + 0][r] = a.x; As[kk + 1][r] = a.y; As[kk + 2][r] = a.z; As[kk + 3][r] = a.w;
    }
    {
      int kk = t >> 4, cc = (t & 15) * 4;
      float4 b = *(const float4*)(B + (size_t)(k0 + kk) * Nd + col0 + cc);
      Bs[kk][cc] = b.x; Bs[kk][cc + 1] = b.y; Bs[kk][cc + 2] = b.z; Bs[kk][cc + 3] = b.w;
    }
    __syncthreads();
#pragma unroll
    for (int kk = 0; kk < BK; ++kk) {
      float ar[8], br[4];
#pragma unroll
      for (int i = 0; i < 8; ++i) ar[i] = As[kk][ty * 8 + i];
#pragma unroll
      for (int j = 0; j < 4; ++j) br[j] = Bs[kk][tx * 4 + j];
#pragma unroll
      for (int i = 0; i < 8; ++i)
#pragma unroll
        for (int j = 0; j < 4; ++j) acc[i][j] += ar[i] * br[j];
    }
    __syncthreads();
  }
#pragma unroll
  for (int i = 0; i < 8; ++i) {
    int r = row0 + ty * 8 + i;
    if (r < M) {
      int c = col0 + tx * 4;
      ushort4 h;
      h.x = f2bf(acc[i][0] + bias[c + 0]);
      h.y = f2bf(acc[i][1] + bias[c + 1]);
      h.z = f2bf(acc[i][2] + bias[c + 2]);
      h.w = f2bf(acc[i][3] + bias[c + 3]);
      *(ushort4*)(C16 + (size_t)r * Nd + c) = h;
    }
  }
}

// ---------------- fused QKVS+Dq bf16 MFMA GEMM, 128x128 tile ---------------
// C[M x 1152] = A'[M x 256] @ Bt^T where A' = LeakyReLU(BN(A)) applied in
// the A-staging (register load + transform + ds_write).  B staged via
// global_load_lds width=16.  K/V written as split planes.
__global__ __launch_bounds__(256) void k_qkvs(
    const ushort_t* __restrict__ A, const ushort_t* __restrict__ Bt,
    const float* __restrict__ bias,
    const float* __restrict__ bnsc, const float* __restrict__ bnsh, float slope,
    ushort_t* __restrict__ Qb16, ushort_t* __restrict__ KVb,
    ushort_t* __restrict__ Sb16, float* __restrict__ Dqb, int M) {
  __shared__ short lds_a[8192];   // 128 x 64 bf16 (swizzled granules)
  __shared__ short lds_b[8192];
  __shared__ float ssc[256], ssh[256];
  int t = threadIdx.x;
  int lane = t & 63, wv = t >> 6;
  int row0 = blockIdx.y * 128, col0 = blockIdx.x * 128;

  ssc[t] = bnsc[t];
  ssh[t] = bnsh[t];

  f32x4 acc[4][4];
#pragma unroll
  for (int im = 0; im < 4; ++im)
#pragma unroll
    for (int in = 0; in < 4; ++in) acc[im][in] = (f32x4){0.f, 0.f, 0.f, 0.f};

  int ln16 = lane & 15, q = lane >> 4;
  int mbase = (wv >> 1) * 64;
  int nbase = (wv & 1) * 64;

  for (int kk = 0; kk < 4; ++kk) {
    int k0 = kk * 64;
    __syncthreads();   // protect previous LDS reads (kk=0: publishes ssc/ssh)
    // stage B via global_load_lds (4 granules/thread)
#pragma unroll
    for (int i = 0; i < 4; ++i) {
      int gi = i * 256 + t;
      int r = gi >> 3, c = (gi & 7) ^ (r & 7);
      gl_lds16(Bt + (size_t)(col0 + r) * 256 + k0 + c * 8, &((int4*)lds_b)[gi]);
    }
    // stage A with BN+LeakyReLU applied (4 granules/thread, register path)
#pragma unroll
    for (int i = 0; i < 4; ++i) {
      int gi = i * 256 + t;
      int r = gi >> 3, c = (gi & 7) ^ (r & 7);
      int gr = row0 + r; if (gr > M - 1) gr = M - 1;
      u16x8 av = *(const u16x8*)(A + (size_t)gr * 256 + k0 + c * 8);
      int ch0 = k0 + c * 8;
      float4 sc0 = *(const float4*)(ssc + ch0);
      float4 sc1 = *(const float4*)(ssc + ch0 + 4);
      float4 sh0 = *(const float4*)(ssh + ch0);
      float4 sh1 = *(const float4*)(ssh + ch0 + 4);
      float v0 = bf2f(av[0]) * sc0.x + sh0.x;
      float v1 = bf2f(av[1]) * sc0.y + sh0.y;
      float v2 = bf2f(av[2]) * sc0.z + sh0.z;
      float v3 = bf2f(av[3]) * sc0.w + sh0.w;
      float v4 = bf2f(av[4]) * sc1.x + sh1.x;
      float v5 = bf2f(av[5]) * sc1.y + sh1.y;
      float v6 = bf2f(av[6]) * sc1.z + sh1.z;
      float v7 = bf2f(av[7]) * sc1.w + sh1.w;
      u16x8 o;
      o[0] = f2bf(v0 >= 0.f ? v0 : slope * v0);
      o[1] = f2bf(v1 >= 0.f ? v1 : slope * v1);
      o[2] = f2bf(v2 >= 0.f ? v2 : slope * v2);
      o[3] = f2bf(v3 >= 0.f ? v3 : slope * v3);
      o[4] = f2bf(v4 >= 0.f ? v4 : slope * v4);
      o[5] = f2bf(v5 >= 0.f ? v5 : slope * v5);
      o[6] = f2bf(v6 >= 0.f ? v6 : slope * v6);
      o[7] = f2bf(v7 >= 0.f ? v7 : slope * v7);
      ((u16x8*)lds_a)[gi] = o;
    }
    __syncthreads();
#pragma unroll
    for (int kc = 0; kc < 2; ++kc) {
      s16x8 af[4], bf[4];
      int cq = kc * 4 + q;
#pragma unroll
      for (int im = 0; im < 4; ++im) {
        int r = mbase + im * 16 + ln16;
        af[im] = ((const s16x8*)lds_a)[r * 8 + (cq ^ (r & 7))];
      }
#pragma unroll
      for (int in = 0; in < 4; ++in) {
        int r = nbase + in * 16 + ln16;
        bf[in] = ((const s16x8*)lds_b)[r * 8 + (cq ^ (r & 7))];
      }
#pragma unroll
      for (int im = 0; im < 4; ++im)
#pragma unroll
        for (int in = 0; in < 4; ++in)
          acc[im][in] = __builtin_amdgcn_mfma_f32_16x16x32_bf16(af[im], bf[in], acc[im][in], 0, 0, 0);
    }
  }

  // epilogue: C[m = q*4+j][n = ln16] per tile; split K/V planes.
#pragma unroll
  for (int in = 0; in < 4; ++in) {
    int ncol = col0 + nbase + in * 16 + ln16;
    float bz = bias[ncol];
#pragma unroll
    for (int im = 0; im < 4; ++im) {
#pragma unroll
      for (int j = 0; j < 4; ++j) {
        int mr = row0 + mbase + im * 16 + q * 4 + j;
        if (mr < M) {
          float v = acc[im][in][j] + bz;
          if (ncol < 256)       Qb16[(size_t)mr * 256 + ncol] = f2bf(v);
          else if (ncol < 512)  KVb[(size_t)mr * 512 + (ncol - 256)] = f2bf(v);
          else if (ncol < 768)  KVb[(size_t)mr * 512 + 256 + (ncol - 512)] = f2bf(v);
          else if (ncol < 1024) Sb16[(size_t)mr * 256 + (ncol - 768)] = f2bf(v);
          else { int j2 = ncol - 1024; if (j2 < 68) Dqb[(size_t)mr * 68 + j2] = v; }
        }
      }
    }
  }
}

// ---------------- attention + beta-gate blend: one node per wave -----------
__global__ __launch_bounds__(256) void k_attn(
    const ushort_t* __restrict__ Qp, const ushort_t* __restrict__ KVm,
    const float* __restrict__ Dqp,
    const float* __restrict__ ea_g, const int* __restrict__ srcA,
    const float* __restrict__ We_l, const float* __restrict__ be_l,
    const float* __restrict__ Wb, const int* __restrict__ row_ptr,
    const int* __restrict__ csr, const ushort_t* __restrict__ Sp,
    ushort_t* __restrict__ xout, int nNodes) {
  __shared__ float sWb[768];
  int t = threadIdx.x;
  sWb[t] = Wb[t];
  sWb[t + 256] = Wb[t + 256];
  sWb[t + 512] = Wb[t + 512];
  __syncthreads();
  int lane = t & 63;
  int t16 = lane & 15;
  int n = blockIdx.x * 4 + (t >> 6);
  if (n >= nNodes) return;

  float4 be4 = *(const float4*)(be_l + 4 * lane);
  ushort4 qh = *(const ushort4*)(Qp + (size_t)n * 256 + 4 * lane);
  float4 qs = make_float4(bf2f(qh.x) * 0.125f, bf2f(qh.y) * 0.125f,
                          bf2f(qh.z) * 0.125f, bf2f(qh.w) * 0.125f);
  float dqv = Dqp[(size_t)n * 68 + lane];
  float qbe = Dqp[(size_t)n * 68 + 64 + (lane >> 4)];
  int beg = row_ptr[n], end = row_ptr[n + 1];

  float m = -INFINITY, dn = 0.f, wa = 0.f;
  float4 ac = make_float4(0.f, 0.f, 0.f, 0.f);

  for (int base = beg; base < end; base += 64) {
    int cnt = min(64, end - base);
    int eL = 0, sL = 0;
    if (lane < cnt) { eL = csr[base + lane]; sL = srcA[eL]; }

    ushort4 kA[4], vA[4], kB[4], vB[4];
    float eatA[4], eatB[4];

    auto ld4 = [&](ushort4* bk, ushort4* bv, float* eat, int g4) {
      if (g4 >= cnt) return;
#pragma unroll
      for (int jj = 0; jj < 4; ++jj) {
        if (g4 + jj < cnt) {
          int e = __shfl(eL, g4 + jj, 64);
          int s = __shfl(sL, g4 + jj, 64);
          eat[jj] = ea_g[(size_t)e * 16 + t16];
          bk[jj] = *(const ushort4*)(KVm + (size_t)s * 512 + 4 * lane);
          bv[jj] = *(const ushort4*)(KVm + (size_t)s * 512 + 256 + 4 * lane);
        } else {
          bk[jj] = make_ushort4(0, 0, 0, 0);
          bv[jj] = make_ushort4(0, 0, 0, 0);
          eat[jj] = 0.f;
        }
      }
    };
    auto proc4 = [&](const ushort4* bk, const ushort4* bv, const float* eat, int g4) {
      float p[4];
#pragma unroll
      for (int jj = 0; jj < 4; ++jj) {
        float part = qs.x * bf2f(bk[jj].x) + qs.y * bf2f(bk[jj].y) +
                     qs.z * bf2f(bk[jj].z) + qs.w * bf2f(bk[jj].w) +
                     eat[jj] * dqv;
        float pj = red16_dpp(part) + qbe;
        p[jj] = (g4 + jj < cnt) ? pj : -INFINITY;
      }
      float gm = fmaxf(fmaxf(p[0], p[1]), fmaxf(p[2], p[3]));
      float mn = fmaxf(m, gm);
      float scl = __expf(m - mn);   // first group: m=-inf -> 0
      m = mn;
      float w0 = __expf(p[0] - mn);
      float w1 = __expf(p[1] - mn);
      float w2 = __expf(p[2] - mn);
      float w3 = __expf(p[3] - mn);
      dn = dn * scl + ((w0 + w1) + (w2 + w3));
      ac.x = ac.x * scl + ((w0 * bf2f(bv[0].x) + w1 * bf2f(bv[1].x)) +
                           (w2 * bf2f(bv[2].x) + w3 * bf2f(bv[3].x)));
      ac.y = ac.y * scl + ((w0 * bf2f(bv[0].y) + w1 * bf2f(bv[1].y)) +
                           (w2 * bf2f(bv[2].y) + w3 * bf2f(bv[3].y)));
      ac.z = ac.z * scl + ((w0 * bf2f(bv[0].z) + w1 * bf2f(bv[1].z)) +
                           (w2 * bf2f(bv[2].z) + w3 * bf2f(bv[3].z)));
      ac.w = ac.w * scl + ((w0 * bf2f(bv[0].w) + w1 * bf2f(bv[1].w)) +
                           (w2 * bf2f(bv[2].w) + w3 * bf2f(bv[3].w)));
      wa = wa * scl + ((w0 * eat[0] + w1 * eat[1]) + (w2 * eat[2] + w3 * eat[3]));
    };

    ld4(kA, vA, eatA, 0);
    for (int g4 = 0; g4 < cnt; g4 += 8) {
      ld4(kB, vB, eatB, g4 + 4);
      proc4(kA, vA, eatA, g4);
      if (g4 + 4 >= cnt) break;
      ld4(kA, vA, eatA, g4 + 8);
      proc4(kB, vB, eatB, g4 + 4);
    }
  }

  // epilogue
  float4 o = make_float4(0.f, 0.f, 0.f, 0.f);
  float wacc = 0.f;
  if (end > beg) {
    float inv = 1.0f / dn;
    o.x = ac.x * inv + be4.x;
    o.y = ac.y * inv + be4.y;
    o.z = ac.z * inv + be4.z;
    o.w = ac.w * inv + be4.w;
    wacc = wa * inv;
  }
  int lanebase = lane & 48;
#pragma unroll
  for (int tt = 0; tt < 16; ++tt) {
    float4 w4 = *(const float4*)(We_l + tt * 256 + 4 * lane);
    float wv = __shfl(wacc, lanebase + tt, 64);
    o.x += wv * w4.x; o.y += wv * w4.y; o.z += wv * w4.z; o.w += wv * w4.w;
  }

  // fused beta-gate blend
  ushort4 rh = *(const ushort4*)(Sp + (size_t)n * 256 + 4 * lane);
  float4 r = make_float4(bf2f(rh.x), bf2f(rh.y), bf2f(rh.z), bf2f(rh.w));
  int c = 4 * lane;
  float z = o.x * sWb[c] + o.y * sWb[c + 1] + o.z * sWb[c + 2] + o.w * sWb[c + 3]
          + r.x * sWb[256 + c] + r.y * sWb[257 + c] + r.z * sWb[258 + c] + r.w * sWb[259 + c]
          + (o.x - r.x) * sWb[512 + c] + (o.y - r.y) * sWb[513 + c]
          + (o.z - r.z) * sWb[514 + c] + (o.w - r.w) * sWb[515 + c];
#pragma unroll
  for (int off = 1; off < 64; off <<= 1) z += __shfl_xor(z, off, 64);
  float beta = 1.0f / (1.0f + __expf(-z));
  ushort4 xh;
  xh.x = f2bf(beta * r.x + (1.f - beta) * o.x);
  xh.y = f2bf(beta * r.y + (1.f - beta) * o.y);
  xh.z = f2bf(beta * r.z + (1.f - beta) * o.z);
  xh.w = f2bf(beta * r.w + (1.f - beta) * o.w);
  *(ushort4*)(xout + (size_t)n * 256 + 4 * lane) = xh;
}

// ---------------- batchnorm (stats + scale/shift) --------------------------
__global__ void k_bnstats(const ushort_t* __restrict__ x16, float* __restrict__ sums,
                          float* __restrict__ sums2, int nRows) {
  int c = threadIdx.x;
  int rpb = (nRows + gridDim.x - 1) / gridDim.x;
  int r0 = blockIdx.x * rpb;
  int r1 = min(nRows, r0 + rpb);
  float s = 0.f, s2 = 0.f;
  for (int r = r0; r < r1; ++r) {
    float v = bf2f(x16[(size_t)r * 256 + c]);
    s += v;
    s2 += v * v;
  }
  atomicAdd(&sums[c], s);
  atomicAdd(&sums2[c], s2);
}

__global__ void k_bnscale(const float* __restrict__ sums, const float* __restrict__ sums2,
                          const float* __restrict__ gamma, const float* __restrict__ beta,
                          float* __restrict__ sc, float* __restrict__ sh, int nRows) {
  int c = threadIdx.x;
  float invN = 1.0f / (float)nRows;
  float mu = sums[c] * invN;
  float var = sums2[c] * invN - mu * mu;
  float s = rsqrtf(var + EPS) * gamma[c];
  sc[c] = s;
  sh[c] = beta[c] - mu * s;
}

__global__ void k_bninit(float* __restrict__ sc, float* __restrict__ sh) {
  int c = threadIdx.x;
  sc[c] = 1.0f;
  sh[c] = 0.0f;
}

// final BN+LeakyReLU apply (layer 3) before pooling, in place
__global__ __launch_bounds__(256) void k_bnapply16(
    ushort_t* __restrict__ x16, const float* __restrict__ sc,
    const float* __restrict__ sh, int nRows) {
  int total4 = nRows * 64;
  for (int i4 = blockIdx.x * 256 + threadIdx.x; i4 < total4; i4 += gridDim.x * 256) {
    int c4 = (i4 & 63) * 4;
    ushort4 xh = *(const ushort4*)(x16 + (size_t)i4 * 4);
    float4 s = *(const float4*)(sc + c4);
    float4 b = *(const float4*)(sh + c4);
    float v0 = bf2f(xh.x) * s.x + b.x;
    float v1 = bf2f(xh.y) * s.y + b.y;
    float v2 = bf2f(xh.z) * s.z + b.z;
    float v3 = bf2f(xh.w) * s.w + b.w;
    v0 = v0 >= 0.f ? v0 : 0.1f * v0;
    v1 = v1 >= 0.f ? v1 : 0.1f * v1;
    v2 = v2 >= 0.f ? v2 : 0.1f * v2;
    v3 = v3 >= 0.f ? v3 : 0.1f * v3;
    ushort4 h;
    h.x = f2bf(v0); h.y = f2bf(v1); h.z = f2bf(v2); h.w = f2bf(v3);
    *(ushort4*)(x16 + (size_t)i4 * 4) = h;
  }
}

// ---------------- pooling + head -------------------------------------------
__global__ void k_pool(const ushort_t* __restrict__ x16, const int* __restrict__ batch,
                       float* __restrict__ pool, int nRows) {
  int c = threadIdx.x;
  int rpb = (nRows + gridDim.x - 1) / gridDim.x;
  int r0 = blockIdx.x * rpb;
  int r1 = min(nRows, r0 + rpb);
  float acc = 0.f;
  int gc = -1;
  for (int r = r0; r < r1; ++r) {
    int g = batch[r];
    if (g != gc) {
      if (gc >= 0) atomicAdd(&pool[gc * 256 + c], acc);
      acc = 0.f;
      gc = g;
    }
    acc += bf2f(x16[(size_t)r * 256 + c]);
  }
  if (gc >= 0) atomicAdd(&pool[gc * 256 + c], acc);
}

// head with inline per-graph counts (batch sorted -> binary search)
__global__ void k_head(const float* __restrict__ pool, const int* __restrict__ batch,
                       const float* __restrict__ hW, const float* __restrict__ hb,
                       float* __restrict__ outp, int nRows) {
  int g = blockIdx.x, lane = threadIdx.x;
  int lo = 0, hi = nRows;
  while (lo < hi) { int mid = (lo + hi) >> 1; if (batch[mid] < g) lo = mid + 1; else hi = mid; }
  int lb = lo;
  lo = 0; hi = nRows;
  while (lo < hi) { int mid = (lo + hi) >> 1; if (batch[mid] < g + 1) lo = mid + 1; else hi = mid; }
  float cnt = fmaxf((float)(lo - lb), 1.0f);
  float z = 0.f;
#pragma unroll
  for (int i = 0; i < 4; ++i) {
    int c = lane + i * 64;
    float s = pool[g * 256 + c];
    z += (s / cnt) * hW[c] + s * hW[256 + c];
  }
#pragma unroll
  for (int off = 1; off < 64; off <<= 1) z += __shfl_xor(z, off, 64);
  if (lane == 0) outp[g] = z + hb[0];
}

// ---------------------------------------------------------------------------
extern "C" void kernel_launch(void* const* d_in, const int* in_sizes, int n_in,
                              void* d_out, int out_size, void* d_ws, size_t ws_size,
                              hipStream_t stream) {
  const float* node_features = (const float*)d_in[0];
  const int*   edge_index    = (const int*)d_in[1];
  const float* edge_attr     = (const float*)d_in[2];
  const int*   batch         = (const int*)d_in[3];
  const float* proj_W  = (const float*)d_in[4];
  const float* proj_b  = (const float*)d_in[5];
  const float* Wq      = (const float*)d_in[6];
  const float* bq      = (const float*)d_in[7];
  const float* Wk      = (const float*)d_in[8];
  const float* bk      = (const float*)d_in[9];
  const float* Wv      = (const float*)d_in[10];
  const float* bv      = (const float*)d_in[11];
  const float* We      = (const float*)d_in[12];
  const float* be      = (const float*)d_in[13];
  const float* Wskip   = (const float*)d_in[14];
  const float* bskip   = (const float*)d_in[15];
  const float* Wbeta   = (const float*)d_in[16];
  const float* bn_gamma= (const float*)d_in[17];
  const float* bn_beta = (const float*)d_in[18];
  const float* head_W  = (const float*)d_in[19];
  const float* head_b  = (const float*)d_in[20];
  float* out_dev = (float*)d_out;

  const int Nn = in_sizes[0] / 64;   // 50000
  const int Ee = in_sizes[1] / 2;    // 500000
  const int Gg = out_size;           // 64

  char* ws = (char*)d_ws;
  size_t off = 0;
  auto alloc = [&](size_t bytes) -> void* {
    void* p = ws + off;
    off += (bytes + 255) & ~(size_t)255;
    return p;
  };
  float*    Dqb    = (float*)alloc((size_t)Nn * 68 * 4);
  ushort_t* xb16   = (ushort_t*)alloc((size_t)Nn * 256 * 2);
  ushort_t* Qb16   = (ushort_t*)alloc((size_t)Nn * 256 * 2);
  ushort_t* Sb16   = (ushort_t*)alloc((size_t)Nn * 256 * 2);
  ushort_t* KVb    = (ushort_t*)alloc((size_t)Nn * 512 * 2);   // K plane | V plane
  ushort_t* Wcat_t = (ushort_t*)alloc((size_t)4 * 1152 * 256 * 2);
  float*    bias_cat = (float*)alloc((size_t)4 * 1152 * 4);
  float*    bnstat = (float*)alloc(512 * 4);
  float*    bnsc   = (float*)alloc(256 * 4);
  float*    bnsh   = (float*)alloc(256 * 4);
  float*    idsc   = (float*)alloc(256 * 4);
  float*    idsh   = (float*)alloc(256 * 4);
  float*    pool   = (float*)alloc((size_t)Gg * 256 * 4);
  int* deg     = (int*)alloc((size_t)Nn * 4);
  int* fill    = (int*)alloc((size_t)Nn * 4);
  int* row_ptr = (int*)alloc((size_t)(Nn + 1) * 4);
  int* csr     = (int*)alloc((size_t)Ee * 4);
  (void)ws_size; (void)n_in;

  const int* srcA = edge_index;
  const int* dstA = edge_index + Ee;

  // CSR build by dst
  hipMemsetAsync(deg, 0, (size_t)Nn * 4, stream);
  hipMemsetAsync(fill, 0, (size_t)Nn * 4, stream);
  k_count<<<(Ee + 255) / 256, 256, 0, stream>>>(dstA, deg, Ee);
  k_scan<<<1, 1024, 0, stream>>>(deg, row_ptr, Nn);
  k_scatter<<<(Ee + 255) / 256, 256, 0, stream>>>(dstA, row_ptr, fill, csr, Ee);

  // weight/bias conversion (bf16, transposed concat) + composite dq rows
  k_wconv<<<dim3(8, 8, 16), dim3(32, 8), 0, stream>>>(Wq, Wk, Wv, Wskip, Wcat_t);
  k_bconv<<<16, 256, 0, stream>>>(bq, bk, bv, bskip, bias_cat);
  k_mkdq<<<dim3(68, 4), 256, 0, stream>>>(Wq, bq, We, be, Wcat_t, bias_cat);
  k_bninit<<<1, 256, 0, stream>>>(idsc, idsh);

  // input projection (fp32 -> bf16)
  dim3 gemm_grid(256 / BN, (Nn + BM - 1) / BM);
  k_gemm<<<gemm_grid, 256, 0, stream>>>(node_features, proj_W, proj_b, xb16, Nn, 64, 256);

  int nodeBlocks = (Nn + 3) / 4;
  dim3 qkvs_grid(9, (Nn + 127) / 128);
  for (int l = 0; l < 4; ++l) {
    k_qkvs<<<qkvs_grid, 256, 0, stream>>>(
        xb16, Wcat_t + (size_t)l * (1152 * 256), bias_cat + l * 1152,
        (l == 0) ? idsc : bnsc, (l == 0) ? idsh : bnsh, (l == 0) ? 1.0f : 0.1f,
        Qb16, KVb, Sb16, Dqb, Nn);

    k_attn<<<nodeBlocks, 256, 0, stream>>>(Qb16, KVb, Dqb, edge_attr, srcA,
                                           We + (size_t)l * 4096, be + l * 256,
                                           Wbeta + (size_t)l * 768,
                                           row_ptr, csr, Sb16, xb16, Nn);

    hipMemsetAsync(bnstat, 0, 512 * 4, stream);
    k_bnstats<<<512, 256, 0, stream>>>(xb16, bnstat, bnstat + 256, Nn);
    k_bnscale<<<1, 256, 0, stream>>>(bnstat, bnstat + 256,
                                     bn_gamma + l * 256, bn_beta + l * 256,
                                     bnsc, bnsh, Nn);
  }

  // layer-3 BN+LeakyReLU, then pooling + head
  k_bnapply16<<<512, 256, 0, stream>>>(xb16, bnsc, bnsh, Nn);
  hipMemsetAsync(pool, 0, (size_t)Gg * 256 * 4, stream);
  k_pool<<<256, 256, 0, stream>>>(xb16, batch, pool, Nn);
  k_head<<<Gg, 64, 0, stream>>>(pool, batch, head_W, head_b, out_dev, Nn);
}

// Round 12
// 1249.637 us; speedup vs baseline: 1.1675x; 1.1675x over previous
//
#include <hip/hip_runtime.h>
#include <math.h>

// ---------------------------------------------------------------------------
// AnticipatoryRestaurantGNN round 12:
//  - k_qkvs: R9 structure (global_load_lds A+B, 32KB LDS, low VGPR) with the
//    MFMA OPERAND SWAP: mfma(bf, af) puts lane=row, regs=4 consecutive cols,
//    so the epilogue does ushort4 (8B) contiguous stores -> full-line write
//    combining (R11's 2B scattered stores caused WRITE 182MB vs 113 logical).
//  - split K/V planes kept; Dq stored bf16 in padded 128-col rows.
//  - BN reverted to separate streaming bnstats+bnapply (R11's fused path cost
//    VGPR 104 / occupancy 21% -> net loss).
// ---------------------------------------------------------------------------

#define EPS 1e-5f
typedef unsigned short ushort_t;
typedef unsigned int uint_t;

using f32x4 = __attribute__((ext_vector_type(4))) float;
using s16x8 = __attribute__((ext_vector_type(8))) short;
using u16x8 = __attribute__((ext_vector_type(8))) unsigned short;

__device__ __forceinline__ ushort_t f2bf(float f) {
  union { float f; uint_t u; } v; v.f = f;
  uint_t u = v.u;
  uint_t r = (u + 0x7FFFu + ((u >> 16) & 1u)) >> 16;   // RNE
  return (ushort_t)r;
}
__device__ __forceinline__ float bf2f(ushort_t h) {
  union { uint_t u; float f; } v; v.u = ((uint_t)h) << 16;
  return v.f;
}

__device__ __forceinline__ void gl_lds16(const void* g, void* l) {
  __builtin_amdgcn_global_load_lds(
      (const __attribute__((address_space(1))) void*)g,
      (__attribute__((address_space(3))) void*)l, 16, 0, 0);
}

// DPP rotate-add reduction over each 16-lane row (per-head), pure VALU.
template <int CTRL>
__device__ __forceinline__ float dpp_add(float x) {
  int v = __builtin_amdgcn_update_dpp(0, __float_as_int(x), CTRL, 0xF, 0xF, true);
  return x + __int_as_float(v);
}
__device__ __forceinline__ float red16_dpp(float x) {
  x = dpp_add<0x121>(x);   // row_ror:1
  x = dpp_add<0x122>(x);   // row_ror:2
  x = dpp_add<0x124>(x);   // row_ror:4
  x = dpp_add<0x128>(x);   // row_ror:8
  return x;
}

// ---------------- CSR build (by dst; dst reused across all 4 layers) -------
__global__ void k_count(const int* __restrict__ dst, int* __restrict__ deg, int n) {
  int i = blockIdx.x * 256 + threadIdx.x;
  if (i < n) atomicAdd(&deg[dst[i]], 1);
}

__global__ void k_scan(const int* __restrict__ deg, int* __restrict__ row_ptr, int n) {
  __shared__ int wsum[16];
  __shared__ int carry_s;
  int t = threadIdx.x, lane = t & 63, w = t >> 6;
  if (t == 0) { carry_s = 0; row_ptr[0] = 0; }
  __syncthreads();
  for (int base = 0; base < n; base += 1024) {
    int v = (base + t < n) ? deg[base + t] : 0;
    int x = v;
#pragma unroll
    for (int off = 1; off < 64; off <<= 1) {
      int y = __shfl_up(x, off, 64);
      if (lane >= off) x += y;
    }
    if (lane == 63) wsum[w] = x;
    __syncthreads();
    if (w == 0 && lane < 16) {
      int s = wsum[lane];
#pragma unroll
      for (int off = 1; off < 16; off <<= 1) {
        int y = __shfl_up(s, off, 64);
        if (lane >= off) s += y;
      }
      wsum[lane] = s;
    }
    __syncthreads();
    int add = (w > 0) ? wsum[w - 1] : 0;
    int incl = x + add + carry_s;
    if (base + t < n) row_ptr[base + t + 1] = incl;
    __syncthreads();
    if (t == 1023) carry_s = incl;
    __syncthreads();
  }
}

__global__ void k_scatter(const int* __restrict__ dst, const int* __restrict__ row_ptr,
                          int* __restrict__ fill, int* __restrict__ csr, int n) {
  int i = blockIdx.x * 256 + threadIdx.x;
  if (i < n) {
    int d = dst[i];
    int pos = atomicAdd(&fill[d], 1);
    csr[row_ptr[d] + pos] = i;
  }
}

// ---------------- weight convert: Wcat_t[l][n=1152][k=256] bf16 ------------
__global__ void k_wconv(const float* __restrict__ Wq, const float* __restrict__ Wk,
                        const float* __restrict__ Wv, const float* __restrict__ Ws,
                        ushort_t* __restrict__ Wcat_t) {
  __shared__ float tile[32][33];
  int l = blockIdx.z >> 2, sel = blockIdx.z & 3;
  const float* W = (sel == 0) ? Wq : (sel == 1) ? Wk : (sel == 2) ? Wv : Ws;
  W += (size_t)l * 65536;
  int k0 = blockIdx.x * 32, n0 = blockIdx.y * 32;
  int tx = threadIdx.x, ty = threadIdx.y;           // 32 x 8
#pragma unroll
  for (int i = 0; i < 32; i += 8) tile[ty + i][tx] = W[(size_t)(k0 + ty + i) * 256 + n0 + tx];
  __syncthreads();
  ushort_t* dst = Wcat_t + (size_t)l * (1152 * 256) + (size_t)(sel * 256 + n0) * 256 + k0;
#pragma unroll
  for (int i = 0; i < 32; i += 8) dst[(size_t)(ty + i) * 256 + tx] = f2bf(tile[tx][ty + i]);
}

// composite rows 1024..1091: M[ci][j] = sum_{c in head(j)} Wq[ci][c]*w2[c]
__global__ void k_mkdq(const float* __restrict__ Wq, const float* __restrict__ bq,
                       const float* __restrict__ We, const float* __restrict__ be,
                       ushort_t* __restrict__ Wcat_t, float* __restrict__ bias_cat) {
  int j = blockIdx.x;        // 0..67
  int l = blockIdx.y;        // 0..3
  int ci = threadIdx.x;      // 0..255
  __shared__ float w2[64];
  int h = (j < 64) ? (j >> 4) : (j - 64);
  if (ci < 64) {
    float v;
    if (j < 64) v = We[(size_t)l * 4096 + (j & 15) * 256 + h * 64 + ci];
    else        v = be[l * 256 + h * 64 + ci];
    w2[ci] = v * 0.125f;
  }
  __syncthreads();
  const float* Wq_l = Wq + (size_t)l * 65536;
  float acc = 0.f;
#pragma unroll 8
  for (int c = 0; c < 64; ++c) acc += Wq_l[(size_t)ci * 256 + h * 64 + c] * w2[c];
  Wcat_t[(size_t)l * (1152 * 256) + (size_t)(1024 + j) * 256 + ci] = f2bf(acc);
  if (ci == 0) {
    const float* bq_l = bq + l * 256;
    float d0 = 0.f;
    for (int c = 0; c < 64; ++c) d0 += bq_l[h * 64 + c] * w2[c];
    bias_cat[l * 1152 + 1024 + j] = d0;
  }
}

__global__ void k_bconv(const float* __restrict__ bq, const float* __restrict__ bk,
                        const float* __restrict__ bv, const float* __restrict__ bs,
                        float* __restrict__ bias_cat) {
  int idx = blockIdx.x * 256 + threadIdx.x;   // 4096 total
  if (idx >= 4096) return;
  int l = idx >> 10, rest = idx & 1023, sel = rest >> 8, c = rest & 255;
  const float* p = (sel == 0) ? bq : (sel == 1) ? bk : (sel == 2) ? bv : bs;
  bias_cat[l * 1152 + rest] = p[l * 256 + c];
}

// ---------------- fp32 tiled GEMM (input projection only, bf16 out) --------
#define BM 128
#define BN 64
#define BK 16
__global__ __launch_bounds__(256) void k_gemm(
    const float* __restrict__ A, const float* __restrict__ B,
    const float* __restrict__ bias, ushort_t* __restrict__ C16,
    int M, int Kd, int Nd) {
  __shared__ float As[BK][BM + 4];
  __shared__ float Bs[BK][BN + 4];
  int t = threadIdx.x;
  int tx = t & 15, ty = t >> 4;
  int row0 = blockIdx.y * BM, col0 = blockIdx.x * BN;
  float acc[8][4] = {};
  for (int k0 = 0; k0 < Kd; k0 += BK) {
#pragma unroll
    for (int i = 0; i < 2; ++i) {
      int idx = t + i * 256;
      int r = idx >> 2, kk = (idx & 3) * 4;
      float4 a = make_float4(0.f, 0.f, 0.f, 0.f);
      if (row0 + r < M) a = *(const float4*)(A + (size_t)(row0 + r) * Kd + k0 + kk);
      As[kk + 0][r] = a.x; As[kk + 1][r] = a.y; As[kk + 2][r] = a.z; As[kk + 3][r] = a.w;
    }
    {
      int kk = t >> 4, cc = (t & 15) * 4;
      float4 b = *(const float4*)(B + (size_t)(k0 + kk) * Nd + col0 + cc);
      Bs[kk][cc] = b.x; Bs[kk][cc + 1] = b.y; Bs[kk][cc + 2] = b.z; Bs[kk][cc + 3] = b.w;
    }
    __syncthreads();
#pragma unroll
    for (int kk = 0; kk < BK; ++kk) {
      float ar[8], br[4];
#pragma unroll
      for (int i = 0; i < 8; ++i) ar[i] = As[kk][ty * 8 + i];
#pragma unroll
      for (int j = 0; j < 4; ++j) br[j] = Bs[kk][tx * 4 + j];
#pragma unroll
      for (int i = 0; i < 8; ++i)
#pragma unroll
        for (int j = 0; j < 4; ++j) acc[i][j] += ar[i] * br[j];
    }
    __syncthreads();
  }
#pragma unroll
  for (int i = 0; i < 8; ++i) {
    int r = row0 + ty * 8 + i;
    if (r < M) {
      int c = col0 + tx * 4;
      ushort4 h;
      h.x = f2bf(acc[i][0] + bias[c + 0]);
      h.y = f2bf(acc[i][1] + bias[c + 1]);
      h.z = f2bf(acc[i][2] + bias[c + 2]);
      h.w = f2bf(acc[i][3] + bias[c + 3]);
      *(ushort4*)(C16 + (size_t)r * Nd + c) = h;
    }
  }
}

// ---------------- fused QKVS+Dq bf16 MFMA GEMM, 128x128 tile ---------------
// C[M x 1152] = A[M x 256] @ Bt^T.  OPERAND-SWAPPED MFMA: mfma(bf, af, acc)
// gives acc[im][in][j] = C[m = mbase+im*16+ln16][n = nbase+in*16+q*4+j]
// -> per lane 4 consecutive cols of one row -> ushort4 contiguous stores.
__global__ __launch_bounds__(256) void k_qkvs(
    const ushort_t* __restrict__ A, const ushort_t* __restrict__ Bt,
    const float* __restrict__ bias, ushort_t* __restrict__ Qb16,
    ushort_t* __restrict__ KVb, ushort_t* __restrict__ Sb16,
    ushort_t* __restrict__ Dqb16, int M) {
  __shared__ short lds_a[8192];   // 128 x 64 bf16 (swizzled granules)
  __shared__ short lds_b[8192];
  int t = threadIdx.x;
  int lane = t & 63, wv = t >> 6;
  int row0 = blockIdx.y * 128, col0 = blockIdx.x * 128;

  f32x4 acc[4][4];
#pragma unroll
  for (int im = 0; im < 4; ++im)
#pragma unroll
    for (int in = 0; in < 4; ++in) acc[im][in] = (f32x4){0.f, 0.f, 0.f, 0.f};

  int ln16 = lane & 15, q = lane >> 4;
  int mbase = (wv >> 1) * 64;
  int nbase = (wv & 1) * 64;

  for (int kk = 0; kk < 4; ++kk) {
    int k0 = kk * 64;
    __syncthreads();          // protect previous iteration's LDS reads
#pragma unroll
    for (int i = 0; i < 4; ++i) {
      int gi = i * 256 + t;
      int r = gi >> 3, c = (gi & 7) ^ (r & 7);
      int gr = row0 + r; if (gr > M - 1) gr = M - 1;
      gl_lds16(A + (size_t)gr * 256 + k0 + c * 8, &((int4*)lds_a)[gi]);
      gl_lds16(Bt + (size_t)(col0 + r) * 256 + k0 + c * 8, &((int4*)lds_b)[gi]);
    }
    __syncthreads();          // drains vmcnt(0) then barrier
#pragma unroll
    for (int kc = 0; kc < 2; ++kc) {
      s16x8 af[4], bf[4];
      int cq = kc * 4 + q;
#pragma unroll
      for (int im = 0; im < 4; ++im) {
        int r = mbase + im * 16 + ln16;
        af[im] = ((const s16x8*)lds_a)[r * 8 + (cq ^ (r & 7))];
      }
#pragma unroll
      for (int in = 0; in < 4; ++in) {
        int r = nbase + in * 16 + ln16;
        bf[in] = ((const s16x8*)lds_b)[r * 8 + (cq ^ (r & 7))];
      }
#pragma unroll
      for (int im = 0; im < 4; ++im)
#pragma unroll
        for (int in = 0; in < 4; ++in)
          acc[im][in] = __builtin_amdgcn_mfma_f32_16x16x32_bf16(bf[in], af[im], acc[im][in], 0, 0, 0);
    }
  }

  // epilogue: lane holds row m = mbase+im*16+ln16, cols n = nbase+in*16+q*4+j
#pragma unroll
  for (int im = 0; im < 4; ++im) {
    int mr = row0 + mbase + im * 16 + ln16;
    if (mr >= M) continue;
#pragma unroll
    for (int in = 0; in < 4; ++in) {
      int ncol = col0 + nbase + in * 16 + q * 4;
      float4 bz = *(const float4*)(bias + ncol);
      f32x4 a = acc[im][in];
      ushort4 h;
      h.x = f2bf(a[0] + bz.x);
      h.y = f2bf(a[1] + bz.y);
      h.z = f2bf(a[2] + bz.z);
      h.w = f2bf(a[3] + bz.w);
      int lc = ncol & 255;
      if (ncol < 256)       *(ushort4*)(Qb16 + (size_t)mr * 256 + lc) = h;
      else if (ncol < 512)  *(ushort4*)(KVb + (size_t)mr * 512 + lc) = h;
      else if (ncol < 768)  *(ushort4*)(KVb + (size_t)mr * 512 + 256 + lc) = h;
      else if (ncol < 1024) *(ushort4*)(Sb16 + (size_t)mr * 256 + lc) = h;
      else                  *(ushort4*)(Dqb16 + (size_t)mr * 128 + (ncol - 1024)) = h;
    }
  }
}

// ---------------- attention + beta-gate blend: one node per wave -----------
__global__ __launch_bounds__(256) void k_attn(
    const ushort_t* __restrict__ Qp, const ushort_t* __restrict__ KVm,
    const ushort_t* __restrict__ Dqp,
    const float* __restrict__ ea_g, const int* __restrict__ srcA,
    const float* __restrict__ We_l, const float* __restrict__ be_l,
    const float* __restrict__ Wb, const int* __restrict__ row_ptr,
    const int* __restrict__ csr, const ushort_t* __restrict__ Sp,
    ushort_t* __restrict__ xout, int nNodes) {
  __shared__ float sWb[768];
  int t = threadIdx.x;
  sWb[t] = Wb[t];
  sWb[t + 256] = Wb[t + 256];
  sWb[t + 512] = Wb[t + 512];
  __syncthreads();
  int lane = t & 63;
  int t16 = lane & 15;
  int n = blockIdx.x * 4 + (t >> 6);
  if (n >= nNodes) return;

  float4 be4 = *(const float4*)(be_l + 4 * lane);
  ushort4 qh = *(const ushort4*)(Qp + (size_t)n * 256 + 4 * lane);
  float4 qs = make_float4(bf2f(qh.x) * 0.125f, bf2f(qh.y) * 0.125f,
                          bf2f(qh.z) * 0.125f, bf2f(qh.w) * 0.125f);
  float dqv = bf2f(Dqp[(size_t)n * 128 + lane]);
  float qbe = bf2f(Dqp[(size_t)n * 128 + 64 + (lane >> 4)]);
  int beg = row_ptr[n], end = row_ptr[n + 1];

  float m = -INFINITY, dn = 0.f, wa = 0.f;
  float4 ac = make_float4(0.f, 0.f, 0.f, 0.f);

  for (int base = beg; base < end; base += 64) {
    int cnt = min(64, end - base);
    int eL = 0, sL = 0;
    if (lane < cnt) { eL = csr[base + lane]; sL = srcA[eL]; }

    ushort4 kA[4], vA[4], kB[4], vB[4];
    float eatA[4], eatB[4];

    auto ld4 = [&](ushort4* bk, ushort4* bv, float* eat, int g4) {
      if (g4 >= cnt) return;
#pragma unroll
      for (int jj = 0; jj < 4; ++jj) {
        if (g4 + jj < cnt) {
          int e = __shfl(eL, g4 + jj, 64);
          int s = __shfl(sL, g4 + jj, 64);
          eat[jj] = ea_g[(size_t)e * 16 + t16];
          bk[jj] = *(const ushort4*)(KVm + (size_t)s * 512 + 4 * lane);
          bv[jj] = *(const ushort4*)(KVm + (size_t)s * 512 + 256 + 4 * lane);
        } else {
          bk[jj] = make_ushort4(0, 0, 0, 0);
          bv[jj] = make_ushort4(0, 0, 0, 0);
          eat[jj] = 0.f;
        }
      }
    };
    auto proc4 = [&](const ushort4* bk, const ushort4* bv, const float* eat, int g4) {
      float p[4];
#pragma unroll
      for (int jj = 0; jj < 4; ++jj) {
        float part = qs.x * bf2f(bk[jj].x) + qs.y * bf2f(bk[jj].y) +
                     qs.z * bf2f(bk[jj].z) + qs.w * bf2f(bk[jj].w) +
                     eat[jj] * dqv;
        float pj = red16_dpp(part) + qbe;
        p[jj] = (g4 + jj < cnt) ? pj : -INFINITY;
      }
      float gm = fmaxf(fmaxf(p[0], p[1]), fmaxf(p[2], p[3]));
      float mn = fmaxf(m, gm);
      float scl = __expf(m - mn);   // first group: m=-inf -> 0
      m = mn;
      float w0 = __expf(p[0] - mn);
      float w1 = __expf(p[1] - mn);
      float w2 = __expf(p[2] - mn);
      float w3 = __expf(p[3] - mn);
      dn = dn * scl + ((w0 + w1) + (w2 + w3));
      ac.x = ac.x * scl + ((w0 * bf2f(bv[0].x) + w1 * bf2f(bv[1].x)) +
                           (w2 * bf2f(bv[2].x) + w3 * bf2f(bv[3].x)));
      ac.y = ac.y * scl + ((w0 * bf2f(bv[0].y) + w1 * bf2f(bv[1].y)) +
                           (w2 * bf2f(bv[2].y) + w3 * bf2f(bv[3].y)));
      ac.z = ac.z * scl + ((w0 * bf2f(bv[0].z) + w1 * bf2f(bv[1].z)) +
                           (w2 * bf2f(bv[2].z) + w3 * bf2f(bv[3].z)));
      ac.w = ac.w * scl + ((w0 * bf2f(bv[0].w) + w1 * bf2f(bv[1].w)) +
                           (w2 * bf2f(bv[2].w) + w3 * bf2f(bv[3].w)));
      wa = wa * scl + ((w0 * eat[0] + w1 * eat[1]) + (w2 * eat[2] + w3 * eat[3]));
    };

    ld4(kA, vA, eatA, 0);
    for (int g4 = 0; g4 < cnt; g4 += 8) {
      ld4(kB, vB, eatB, g4 + 4);
      proc4(kA, vA, eatA, g4);
      if (g4 + 4 >= cnt) break;
      ld4(kA, vA, eatA, g4 + 8);
      proc4(kB, vB, eatB, g4 + 4);
    }
  }

  // epilogue
  float4 o = make_float4(0.f, 0.f, 0.f, 0.f);
  float wacc = 0.f;
  if (end > beg) {
    float inv = 1.0f / dn;
    o.x = ac.x * inv + be4.x;
    o.y = ac.y * inv + be4.y;
    o.z = ac.z * inv + be4.z;
    o.w = ac.w * inv + be4.w;
    wacc = wa * inv;
  }
  int lanebase = lane & 48;
#pragma unroll
  for (int tt = 0; tt < 16; ++tt) {
    float4 w4 = *(const float4*)(We_l + tt * 256 + 4 * lane);
    float wv = __shfl(wacc, lanebase + tt, 64);
    o.x += wv * w4.x; o.y += wv * w4.y; o.z += wv * w4.z; o.w += wv * w4.w;
  }

  // fused beta-gate blend
  ushort4 rh = *(const ushort4*)(Sp + (size_t)n * 256 + 4 * lane);
  float4 r = make_float4(bf2f(rh.x), bf2f(rh.y), bf2f(rh.z), bf2f(rh.w));
  int c = 4 * lane;
  float z = o.x * sWb[c] + o.y * sWb[c + 1] + o.z * sWb[c + 2] + o.w * sWb[c + 3]
          + r.x * sWb[256 + c] + r.y * sWb[257 + c] + r.z * sWb[258 + c] + r.w * sWb[259 + c]
          + (o.x - r.x) * sWb[512 + c] + (o.y - r.y) * sWb[513 + c]
          + (o.z - r.z) * sWb[514 + c] + (o.w - r.w) * sWb[515 + c];
#pragma unroll
  for (int off = 1; off < 64; off <<= 1) z += __shfl_xor(z, off, 64);
  float beta = 1.0f / (1.0f + __expf(-z));
  ushort4 xh;
  xh.x = f2bf(beta * r.x + (1.f - beta) * o.x);
  xh.y = f2bf(beta * r.y + (1.f - beta) * o.y);
  xh.z = f2bf(beta * r.z + (1.f - beta) * o.z);
  xh.w = f2bf(beta * r.w + (1.f - beta) * o.w);
  *(ushort4*)(xout + (size_t)n * 256 + 4 * lane) = xh;
}

// ---------------- batchnorm (bf16 x) ---------------------------------------
__global__ void k_bnstats(const ushort_t* __restrict__ x16, float* __restrict__ sums,
                          float* __restrict__ sums2, int nRows) {
  int c = threadIdx.x;
  int rpb = (nRows + gridDim.x - 1) / gridDim.x;
  int r0 = blockIdx.x * rpb;
  int r1 = min(nRows, r0 + rpb);
  float s = 0.f, s2 = 0.f;
  for (int r = r0; r < r1; ++r) {
    float v = bf2f(x16[(size_t)r * 256 + c]);
    s += v;
    s2 += v * v;
  }
  atomicAdd(&sums[c], s);
  atomicAdd(&sums2[c], s2);
}

__global__ __launch_bounds__(256) void k_bnapply16(
    ushort_t* __restrict__ x16, const float* __restrict__ sums,
    const float* __restrict__ sums2, const float* __restrict__ gamma,
    const float* __restrict__ betap, int nRows) {
  int total4 = nRows * 64;
  float invN = 1.0f / (float)nRows;
  for (int i4 = blockIdx.x * 256 + threadIdx.x; i4 < total4; i4 += gridDim.x * 256) {
    int c4 = (i4 & 63) * 4;
    ushort4 xh = *(const ushort4*)(x16 + (size_t)i4 * 4);
    float4 s = *(const float4*)(sums + c4);
    float4 s2 = *(const float4*)(sums2 + c4);
    float4 g = *(const float4*)(gamma + c4);
    float4 b = *(const float4*)(betap + c4);
    float mu0 = s.x * invN, mu1 = s.y * invN, mu2 = s.z * invN, mu3 = s.w * invN;
    float sc0 = rsqrtf(s2.x * invN - mu0 * mu0 + EPS) * g.x;
    float sc1 = rsqrtf(s2.y * invN - mu1 * mu1 + EPS) * g.y;
    float sc2 = rsqrtf(s2.z * invN - mu2 * mu2 + EPS) * g.z;
    float sc3 = rsqrtf(s2.w * invN - mu3 * mu3 + EPS) * g.w;
    float v0 = (bf2f(xh.x) - mu0) * sc0 + b.x;
    float v1 = (bf2f(xh.y) - mu1) * sc1 + b.y;
    float v2 = (bf2f(xh.z) - mu2) * sc2 + b.z;
    float v3 = (bf2f(xh.w) - mu3) * sc3 + b.w;
    v0 = v0 >= 0.f ? v0 : 0.1f * v0;
    v1 = v1 >= 0.f ? v1 : 0.1f * v1;
    v2 = v2 >= 0.f ? v2 : 0.1f * v2;
    v3 = v3 >= 0.f ? v3 : 0.1f * v3;
    ushort4 h;
    h.x = f2bf(v0); h.y = f2bf(v1); h.z = f2bf(v2); h.w = f2bf(v3);
    *(ushort4*)(x16 + (size_t)i4 * 4) = h;
  }
}

// ---------------- pooling + head -------------------------------------------
__global__ void k_pool(const ushort_t* __restrict__ x16, const int* __restrict__ batch,
                       float* __restrict__ pool, int nRows) {
  int c = threadIdx.x;
  int rpb = (nRows + gridDim.x - 1) / gridDim.x;
  int r0 = blockIdx.x * rpb;
  int r1 = min(nRows, r0 + rpb);
  float acc = 0.f;
  int gc = -1;
  for (int r = r0; r < r1; ++r) {
    int g = batch[r];
    if (g != gc) {
      if (gc >= 0) atomicAdd(&pool[gc * 256 + c], acc);
      acc = 0.f;
      gc = g;
    }
    acc += bf2f(x16[(size_t)r * 256 + c]);
  }
  if (gc >= 0) atomicAdd(&pool[gc * 256 + c], acc);
}

// head with inline per-graph counts (batch sorted -> binary search)
__global__ void k_head(const float* __restrict__ pool, const int* __restrict__ batch,
                       const float* __restrict__ hW, const float* __restrict__ hb,
                       float* __restrict__ outp, int nRows) {
  int g = blockIdx.x, lane = threadIdx.x;
  int lo = 0, hi = nRows;
  while (lo < hi) { int mid = (lo + hi) >> 1; if (batch[mid] < g) lo = mid + 1; else hi = mid; }
  int lb = lo;
  lo = 0; hi = nRows;
  while (lo < hi) { int mid = (lo + hi) >> 1; if (batch[mid] < g + 1) lo = mid + 1; else hi = mid; }
  float cnt = fmaxf((float)(lo - lb), 1.0f);
  float z = 0.f;
#pragma unroll
  for (int i = 0; i < 4; ++i) {
    int c = lane + i * 64;
    float s = pool[g * 256 + c];
    z += (s / cnt) * hW[c] + s * hW[256 + c];
  }
#pragma unroll
  for (int off = 1; off < 64; off <<= 1) z += __shfl_xor(z, off, 64);
  if (lane == 0) outp[g] = z + hb[0];
}

// ---------------------------------------------------------------------------
extern "C" void kernel_launch(void* const* d_in, const int* in_sizes, int n_in,
                              void* d_out, int out_size, void* d_ws, size_t ws_size,
                              hipStream_t stream) {
  const float* node_features = (const float*)d_in[0];
  const int*   edge_index    = (const int*)d_in[1];
  const float* edge_attr     = (const float*)d_in[2];
  const int*   batch         = (const int*)d_in[3];
  const float* proj_W  = (const float*)d_in[4];
  const float* proj_b  = (const float*)d_in[5];
  const float* Wq      = (const float*)d_in[6];
  const float* bq      = (const float*)d_in[7];
  const float* Wk      = (const float*)d_in[8];
  const float* bk      = (const float*)d_in[9];
  const float* Wv      = (const float*)d_in[10];
  const float* bv      = (const float*)d_in[11];
  const float* We      = (const float*)d_in[12];
  const float* be      = (const float*)d_in[13];
  const float* Wskip   = (const float*)d_in[14];
  const float* bskip   = (const float*)d_in[15];
  const float* Wbeta   = (const float*)d_in[16];
  const float* bn_gamma= (const float*)d_in[17];
  const float* bn_beta = (const float*)d_in[18];
  const float* head_W  = (const float*)d_in[19];
  const float* head_b  = (const float*)d_in[20];
  float* out_dev = (float*)d_out;

  const int Nn = in_sizes[0] / 64;   // 50000
  const int Ee = in_sizes[1] / 2;    // 500000
  const int Gg = out_size;           // 64

  char* ws = (char*)d_ws;
  size_t off = 0;
  auto alloc = [&](size_t bytes) -> void* {
    void* p = ws + off;
    off += (bytes + 255) & ~(size_t)255;
    return p;
  };
  ushort_t* Dqb16  = (ushort_t*)alloc((size_t)Nn * 128 * 2);
  ushort_t* xb16   = (ushort_t*)alloc((size_t)Nn * 256 * 2);
  ushort_t* Qb16   = (ushort_t*)alloc((size_t)Nn * 256 * 2);
  ushort_t* Sb16   = (ushort_t*)alloc((size_t)Nn * 256 * 2);
  ushort_t* KVb    = (ushort_t*)alloc((size_t)Nn * 512 * 2);   // K plane | V plane
  ushort_t* Wcat_t = (ushort_t*)alloc((size_t)4 * 1152 * 256 * 2);
  float*    bias_cat = (float*)alloc((size_t)4 * 1152 * 4);
  float*    bnstat = (float*)alloc(512 * 4);
  float*    pool   = (float*)alloc((size_t)Gg * 256 * 4);
  int* deg     = (int*)alloc((size_t)Nn * 4);
  int* fill    = (int*)alloc((size_t)Nn * 4);
  int* row_ptr = (int*)alloc((size_t)(Nn + 1) * 4);
  int* csr     = (int*)alloc((size_t)Ee * 4);
  (void)ws_size; (void)n_in;

  const int* srcA = edge_index;
  const int* dstA = edge_index + Ee;

  // CSR build by dst
  hipMemsetAsync(deg, 0, (size_t)Nn * 4, stream);
  hipMemsetAsync(fill, 0, (size_t)Nn * 4, stream);
  k_count<<<(Ee + 255) / 256, 256, 0, stream>>>(dstA, deg, Ee);
  k_scan<<<1, 1024, 0, stream>>>(deg, row_ptr, Nn);
  k_scatter<<<(Ee + 255) / 256, 256, 0, stream>>>(dstA, row_ptr, fill, csr, Ee);

  // weight/bias conversion (bf16, transposed concat) + composite dq rows
  k_wconv<<<dim3(8, 8, 16), dim3(32, 8), 0, stream>>>(Wq, Wk, Wv, Wskip, Wcat_t);
  k_bconv<<<16, 256, 0, stream>>>(bq, bk, bv, bskip, bias_cat);
  k_mkdq<<<dim3(68, 4), 256, 0, stream>>>(Wq, bq, We, be, Wcat_t, bias_cat);

  // input projection (fp32 -> bf16)
  dim3 gemm_grid(256 / BN, (Nn + BM - 1) / BM);
  k_gemm<<<gemm_grid, 256, 0, stream>>>(node_features, proj_W, proj_b, xb16, Nn, 64, 256);

  int nodeBlocks = (Nn + 3) / 4;
  dim3 qkvs_grid(9, (Nn + 127) / 128);
  for (int l = 0; l < 4; ++l) {
    k_qkvs<<<qkvs_grid, 256, 0, stream>>>(xb16, Wcat_t + (size_t)l * (1152 * 256),
                                          bias_cat + l * 1152, Qb16, KVb, Sb16, Dqb16, Nn);

    k_attn<<<nodeBlocks, 256, 0, stream>>>(Qb16, KVb, Dqb16, edge_attr, srcA,
                                           We + (size_t)l * 4096, be + l * 256,
                                           Wbeta + (size_t)l * 768,
                                           row_ptr, csr, Sb16, xb16, Nn);

    hipMemsetAsync(bnstat, 0, 512 * 4, stream);
    k_bnstats<<<512, 256, 0, stream>>>(xb16, bnstat, bnstat + 256, Nn);
    k_bnapply16<<<512, 256, 0, stream>>>(xb16, bnstat, bnstat + 256,
                                         bn_gamma + l * 256, bn_beta + l * 256, Nn);
  }

  hipMemsetAsync(pool, 0, (size_t)Gg * 256 * 4, stream);
  k_pool<<<256, 256, 0, stream>>>(xb16, batch, pool, Nn);
  k_head<<<Gg, 64, 0, stream>>>(pool, batch, head_W, head_b, out_dev, Nn);
}

// Round 13
// 1214.211 us; speedup vs baseline: 1.2015x; 1.0292x over previous
//
#include <hip/hip_runtime.h>
#include <math.h>

// ---------------------------------------------------------------------------
// AnticipatoryRestaurantGNN round 13:
//  - k_attn: depth-3 static buffer rotation (kA/kB/kC) -> prefetch distance
//    ~2 groups (~560 cyc) to cover L3 gather latency; all buffer indices
//    compile-time (no scratch).  VGPR ~72 (was 52) — still under the cliff.
//  - final-layer BN+LeakyReLU fused into k_pool (one fewer 50MB pass).
//  - everything else: R12 (operand-swapped qkvs epilogue, split K/V planes,
//    bf16 end-to-end, dq via GEMM, DPP reductions, block-softmax).
// ---------------------------------------------------------------------------

#define EPS 1e-5f
typedef unsigned short ushort_t;
typedef unsigned int uint_t;

using f32x4 = __attribute__((ext_vector_type(4))) float;
using s16x8 = __attribute__((ext_vector_type(8))) short;
using u16x8 = __attribute__((ext_vector_type(8))) unsigned short;

__device__ __forceinline__ ushort_t f2bf(float f) {
  union { float f; uint_t u; } v; v.f = f;
  uint_t u = v.u;
  uint_t r = (u + 0x7FFFu + ((u >> 16) & 1u)) >> 16;   // RNE
  return (ushort_t)r;
}
__device__ __forceinline__ float bf2f(ushort_t h) {
  union { uint_t u; float f; } v; v.u = ((uint_t)h) << 16;
  return v.f;
}

__device__ __forceinline__ void gl_lds16(const void* g, void* l) {
  __builtin_amdgcn_global_load_lds(
      (const __attribute__((address_space(1))) void*)g,
      (__attribute__((address_space(3))) void*)l, 16, 0, 0);
}

// DPP rotate-add reduction over each 16-lane row (per-head), pure VALU.
template <int CTRL>
__device__ __forceinline__ float dpp_add(float x) {
  int v = __builtin_amdgcn_update_dpp(0, __float_as_int(x), CTRL, 0xF, 0xF, true);
  return x + __int_as_float(v);
}
__device__ __forceinline__ float red16_dpp(float x) {
  x = dpp_add<0x121>(x);   // row_ror:1
  x = dpp_add<0x122>(x);   // row_ror:2
  x = dpp_add<0x124>(x);   // row_ror:4
  x = dpp_add<0x128>(x);   // row_ror:8
  return x;
}

// ---------------- CSR build (by dst; dst reused across all 4 layers) -------
__global__ void k_count(const int* __restrict__ dst, int* __restrict__ deg, int n) {
  int i = blockIdx.x * 256 + threadIdx.x;
  if (i < n) atomicAdd(&deg[dst[i]], 1);
}

__global__ void k_scan(const int* __restrict__ deg, int* __restrict__ row_ptr, int n) {
  __shared__ int wsum[16];
  __shared__ int carry_s;
  int t = threadIdx.x, lane = t & 63, w = t >> 6;
  if (t == 0) { carry_s = 0; row_ptr[0] = 0; }
  __syncthreads();
  for (int base = 0; base < n; base += 1024) {
    int v = (base + t < n) ? deg[base + t] : 0;
    int x = v;
#pragma unroll
    for (int off = 1; off < 64; off <<= 1) {
      int y = __shfl_up(x, off, 64);
      if (lane >= off) x += y;
    }
    if (lane == 63) wsum[w] = x;
    __syncthreads();
    if (w == 0 && lane < 16) {
      int s = wsum[lane];
#pragma unroll
      for (int off = 1; off < 16; off <<= 1) {
        int y = __shfl_up(s, off, 64);
        if (lane >= off) s += y;
      }
      wsum[lane] = s;
    }
    __syncthreads();
    int add = (w > 0) ? wsum[w - 1] : 0;
    int incl = x + add + carry_s;
    if (base + t < n) row_ptr[base + t + 1] = incl;
    __syncthreads();
    if (t == 1023) carry_s = incl;
    __syncthreads();
  }
}

__global__ void k_scatter(const int* __restrict__ dst, const int* __restrict__ row_ptr,
                          int* __restrict__ fill, int* __restrict__ csr, int n) {
  int i = blockIdx.x * 256 + threadIdx.x;
  if (i < n) {
    int d = dst[i];
    int pos = atomicAdd(&fill[d], 1);
    csr[row_ptr[d] + pos] = i;
  }
}

// ---------------- weight convert: Wcat_t[l][n=1152][k=256] bf16 ------------
__global__ void k_wconv(const float* __restrict__ Wq, const float* __restrict__ Wk,
                        const float* __restrict__ Wv, const float* __restrict__ Ws,
                        ushort_t* __restrict__ Wcat_t) {
  __shared__ float tile[32][33];
  int l = blockIdx.z >> 2, sel = blockIdx.z & 3;
  const float* W = (sel == 0) ? Wq : (sel == 1) ? Wk : (sel == 2) ? Wv : Ws;
  W += (size_t)l * 65536;
  int k0 = blockIdx.x * 32, n0 = blockIdx.y * 32;
  int tx = threadIdx.x, ty = threadIdx.y;           // 32 x 8
#pragma unroll
  for (int i = 0; i < 32; i += 8) tile[ty + i][tx] = W[(size_t)(k0 + ty + i) * 256 + n0 + tx];
  __syncthreads();
  ushort_t* dst = Wcat_t + (size_t)l * (1152 * 256) + (size_t)(sel * 256 + n0) * 256 + k0;
#pragma unroll
  for (int i = 0; i < 32; i += 8) dst[(size_t)(ty + i) * 256 + tx] = f2bf(tile[tx][ty + i]);
}

// composite rows 1024..1091: M[ci][j] = sum_{c in head(j)} Wq[ci][c]*w2[c]
__global__ void k_mkdq(const float* __restrict__ Wq, const float* __restrict__ bq,
                       const float* __restrict__ We, const float* __restrict__ be,
                       ushort_t* __restrict__ Wcat_t, float* __restrict__ bias_cat) {
  int j = blockIdx.x;        // 0..67
  int l = blockIdx.y;        // 0..3
  int ci = threadIdx.x;      // 0..255
  __shared__ float w2[64];
  int h = (j < 64) ? (j >> 4) : (j - 64);
  if (ci < 64) {
    float v;
    if (j < 64) v = We[(size_t)l * 4096 + (j & 15) * 256 + h * 64 + ci];
    else        v = be[l * 256 + h * 64 + ci];
    w2[ci] = v * 0.125f;
  }
  __syncthreads();
  const float* Wq_l = Wq + (size_t)l * 65536;
  float acc = 0.f;
#pragma unroll 8
  for (int c = 0; c < 64; ++c) acc += Wq_l[(size_t)ci * 256 + h * 64 + c] * w2[c];
  Wcat_t[(size_t)l * (1152 * 256) + (size_t)(1024 + j) * 256 + ci] = f2bf(acc);
  if (ci == 0) {
    const float* bq_l = bq + l * 256;
    float d0 = 0.f;
    for (int c = 0; c < 64; ++c) d0 += bq_l[h * 64 + c] * w2[c];
    bias_cat[l * 1152 + 1024 + j] = d0;
  }
}

__global__ void k_bconv(const float* __restrict__ bq, const float* __restrict__ bk,
                        const float* __restrict__ bv, const float* __restrict__ bs,
                        float* __restrict__ bias_cat) {
  int idx = blockIdx.x * 256 + threadIdx.x;   // 4096 total
  if (idx >= 4096) return;
  int l = idx >> 10, rest = idx & 1023, sel = rest >> 8, c = rest & 255;
  const float* p = (sel == 0) ? bq : (sel == 1) ? bk : (sel == 2) ? bv : bs;
  bias_cat[l * 1152 + rest] = p[l * 256 + c];
}

// ---------------- fp32 tiled GEMM (input projection only, bf16 out) --------
#define BM 128
#define BN 64
#define BK 16
__global__ __launch_bounds__(256) void k_gemm(
    const float* __restrict__ A, const float* __restrict__ B,
    const float* __restrict__ bias, ushort_t* __restrict__ C16,
    int M, int Kd, int Nd) {
  __shared__ float As[BK][BM + 4];
  __shared__ float Bs[BK][BN + 4];
  int t = threadIdx.x;
  int tx = t & 15, ty = t >> 4;
  int row0 = blockIdx.y * BM, col0 = blockIdx.x * BN;
  float acc[8][4] = {};
  for (int k0 = 0; k0 < Kd; k0 += BK) {
#pragma unroll
    for (int i = 0; i < 2; ++i) {
      int idx = t + i * 256;
      int r = idx >> 2, kk = (idx & 3) * 4;
      float4 a = make_float4(0.f, 0.f, 0.f, 0.f);
      if (row0 + r < M) a = *(const float4*)(A + (size_t)(row0 + r) * Kd + k0 + kk);
      As[kk + 0][r] = a.x; As[kk + 1][r] = a.y; As[kk + 2][r] = a.z; As[kk + 3][r] = a.w;
    }
    {
      int kk = t >> 4, cc = (t & 15) * 4;
      float4 b = *(const float4*)(B + (size_t)(k0 + kk) * Nd + col0 + cc);
      Bs[kk][cc] = b.x; Bs[kk][cc + 1] = b.y; Bs[kk][cc + 2] = b.z; Bs[kk][cc + 3] = b.w;
    }
    __syncthreads();
#pragma unroll
    for (int kk = 0; kk < BK; ++kk) {
      float ar[8], br[4];
#pragma unroll
      for (int i = 0; i < 8; ++i) ar[i] = As[kk][ty * 8 + i];
#pragma unroll
      for (int j = 0; j < 4; ++j) br[j] = Bs[kk][tx * 4 + j];
#pragma unroll
      for (int i = 0; i < 8; ++i)
#pragma unroll
        for (int j = 0; j < 4; ++j) acc[i][j] += ar[i] * br[j];
    }
    __syncthreads();
  }
#pragma unroll
  for (int i = 0; i < 8; ++i) {
    int r = row0 + ty * 8 + i;
    if (r < M) {
      int c = col0 + tx * 4;
      ushort4 h;
      h.x = f2bf(acc[i][0] + bias[c + 0]);
      h.y = f2bf(acc[i][1] + bias[c + 1]);
      h.z = f2bf(acc[i][2] + bias[c + 2]);
      h.w = f2bf(acc[i][3] + bias[c + 3]);
      *(ushort4*)(C16 + (size_t)r * Nd + c) = h;
    }
  }
}

// ---------------- fused QKVS+Dq bf16 MFMA GEMM, 128x128 tile ---------------
// OPERAND-SWAPPED MFMA: mfma(bf, af, acc) -> lane=row, regs=4 consecutive
// cols -> ushort4 contiguous stores (full-line write combining).
__global__ __launch_bounds__(256) void k_qkvs(
    const ushort_t* __restrict__ A, const ushort_t* __restrict__ Bt,
    const float* __restrict__ bias, ushort_t* __restrict__ Qb16,
    ushort_t* __restrict__ KVb, ushort_t* __restrict__ Sb16,
    ushort_t* __restrict__ Dqb16, int M) {
  __shared__ short lds_a[8192];   // 128 x 64 bf16 (swizzled granules)
  __shared__ short lds_b[8192];
  int t = threadIdx.x;
  int lane = t & 63, wv = t >> 6;
  int row0 = blockIdx.y * 128, col0 = blockIdx.x * 128;

  f32x4 acc[4][4];
#pragma unroll
  for (int im = 0; im < 4; ++im)
#pragma unroll
    for (int in = 0; in < 4; ++in) acc[im][in] = (f32x4){0.f, 0.f, 0.f, 0.f};

  int ln16 = lane & 15, q = lane >> 4;
  int mbase = (wv >> 1) * 64;
  int nbase = (wv & 1) * 64;

  for (int kk = 0; kk < 4; ++kk) {
    int k0 = kk * 64;
    __syncthreads();          // protect previous iteration's LDS reads
#pragma unroll
    for (int i = 0; i < 4; ++i) {
      int gi = i * 256 + t;
      int r = gi >> 3, c = (gi & 7) ^ (r & 7);
      int gr = row0 + r; if (gr > M - 1) gr = M - 1;
      gl_lds16(A + (size_t)gr * 256 + k0 + c * 8, &((int4*)lds_a)[gi]);
      gl_lds16(Bt + (size_t)(col0 + r) * 256 + k0 + c * 8, &((int4*)lds_b)[gi]);
    }
    __syncthreads();          // drains vmcnt(0) then barrier
#pragma unroll
    for (int kc = 0; kc < 2; ++kc) {
      s16x8 af[4], bf[4];
      int cq = kc * 4 + q;
#pragma unroll
      for (int im = 0; im < 4; ++im) {
        int r = mbase + im * 16 + ln16;
        af[im] = ((const s16x8*)lds_a)[r * 8 + (cq ^ (r & 7))];
      }
#pragma unroll
      for (int in = 0; in < 4; ++in) {
        int r = nbase + in * 16 + ln16;
        bf[in] = ((const s16x8*)lds_b)[r * 8 + (cq ^ (r & 7))];
      }
#pragma unroll
      for (int im = 0; im < 4; ++im)
#pragma unroll
        for (int in = 0; in < 4; ++in)
          acc[im][in] = __builtin_amdgcn_mfma_f32_16x16x32_bf16(bf[in], af[im], acc[im][in], 0, 0, 0);
    }
  }

  // epilogue: lane holds row m = mbase+im*16+ln16, cols n = nbase+in*16+q*4+j
#pragma unroll
  for (int im = 0; im < 4; ++im) {
    int mr = row0 + mbase + im * 16 + ln16;
    if (mr >= M) continue;
#pragma unroll
    for (int in = 0; in < 4; ++in) {
      int ncol = col0 + nbase + in * 16 + q * 4;
      float4 bz = *(const float4*)(bias + ncol);
      f32x4 a = acc[im][in];
      ushort4 h;
      h.x = f2bf(a[0] + bz.x);
      h.y = f2bf(a[1] + bz.y);
      h.z = f2bf(a[2] + bz.z);
      h.w = f2bf(a[3] + bz.w);
      int lc = ncol & 255;
      if (ncol < 256)       *(ushort4*)(Qb16 + (size_t)mr * 256 + lc) = h;
      else if (ncol < 512)  *(ushort4*)(KVb + (size_t)mr * 512 + lc) = h;
      else if (ncol < 768)  *(ushort4*)(KVb + (size_t)mr * 512 + 256 + lc) = h;
      else if (ncol < 1024) *(ushort4*)(Sb16 + (size_t)mr * 256 + lc) = h;
      else                  *(ushort4*)(Dqb16 + (size_t)mr * 128 + (ncol - 1024)) = h;
    }
  }
}

// ---------------- attention + beta-gate blend: one node per wave -----------
// Block-softmax per 4-edge group, DPP reductions, depth-3 static buffer
// rotation (kA/kB/kC) for ~2-group prefetch distance.
__global__ __launch_bounds__(256) void k_attn(
    const ushort_t* __restrict__ Qp, const ushort_t* __restrict__ KVm,
    const ushort_t* __restrict__ Dqp,
    const float* __restrict__ ea_g, const int* __restrict__ srcA,
    const float* __restrict__ We_l, const float* __restrict__ be_l,
    const float* __restrict__ Wb, const int* __restrict__ row_ptr,
    const int* __restrict__ csr, const ushort_t* __restrict__ Sp,
    ushort_t* __restrict__ xout, int nNodes) {
  __shared__ float sWb[768];
  int t = threadIdx.x;
  sWb[t] = Wb[t];
  sWb[t + 256] = Wb[t + 256];
  sWb[t + 512] = Wb[t + 512];
  __syncthreads();
  int lane = t & 63;
  int t16 = lane & 15;
  int n = blockIdx.x * 4 + (t >> 6);
  if (n >= nNodes) return;

  float4 be4 = *(const float4*)(be_l + 4 * lane);
  ushort4 qh = *(const ushort4*)(Qp + (size_t)n * 256 + 4 * lane);
  float4 qs = make_float4(bf2f(qh.x) * 0.125f, bf2f(qh.y) * 0.125f,
                          bf2f(qh.z) * 0.125f, bf2f(qh.w) * 0.125f);
  float dqv = bf2f(Dqp[(size_t)n * 128 + lane]);
  float qbe = bf2f(Dqp[(size_t)n * 128 + 64 + (lane >> 4)]);
  int beg = row_ptr[n], end = row_ptr[n + 1];

  float m = -INFINITY, dn = 0.f, wa = 0.f;
  float4 ac = make_float4(0.f, 0.f, 0.f, 0.f);

  for (int base = beg; base < end; base += 64) {
    int cnt = min(64, end - base);
    int eL = 0, sL = 0;
    if (lane < cnt) { eL = csr[base + lane]; sL = srcA[eL]; }

    ushort4 kA[4], vA[4], kB[4], vB[4], kC[4], vC[4];
    float eatA[4], eatB[4], eatC[4];

    auto ld4 = [&](ushort4* bk, ushort4* bv, float* eat, int g4) {
      if (g4 >= cnt) return;
#pragma unroll
      for (int jj = 0; jj < 4; ++jj) {
        if (g4 + jj < cnt) {
          int e = __shfl(eL, g4 + jj, 64);
          int s = __shfl(sL, g4 + jj, 64);
          eat[jj] = ea_g[(size_t)e * 16 + t16];
          bk[jj] = *(const ushort4*)(KVm + (size_t)s * 512 + 4 * lane);
          bv[jj] = *(const ushort4*)(KVm + (size_t)s * 512 + 256 + 4 * lane);
        } else {
          bk[jj] = make_ushort4(0, 0, 0, 0);
          bv[jj] = make_ushort4(0, 0, 0, 0);
          eat[jj] = 0.f;
        }
      }
    };
    auto proc4 = [&](const ushort4* bk, const ushort4* bv, const float* eat, int g4) {
      float p[4];
#pragma unroll
      for (int jj = 0; jj < 4; ++jj) {
        float part = qs.x * bf2f(bk[jj].x) + qs.y * bf2f(bk[jj].y) +
                     qs.z * bf2f(bk[jj].z) + qs.w * bf2f(bk[jj].w) +
                     eat[jj] * dqv;
        float pj = red16_dpp(part) + qbe;
        p[jj] = (g4 + jj < cnt) ? pj : -INFINITY;
      }
      float gm = fmaxf(fmaxf(p[0], p[1]), fmaxf(p[2], p[3]));
      float mn = fmaxf(m, gm);
      float scl = __expf(m - mn);   // first group: m=-inf -> 0
      m = mn;
      float w0 = __expf(p[0] - mn);
      float w1 = __expf(p[1] - mn);
      float w2 = __expf(p[2] - mn);
      float w3 = __expf(p[3] - mn);
      dn = dn * scl + ((w0 + w1) + (w2 + w3));
      ac.x = ac.x * scl + ((w0 * bf2f(bv[0].x) + w1 * bf2f(bv[1].x)) +
                           (w2 * bf2f(bv[2].x) + w3 * bf2f(bv[3].x)));
      ac.y = ac.y * scl + ((w0 * bf2f(bv[0].y) + w1 * bf2f(bv[1].y)) +
                           (w2 * bf2f(bv[2].y) + w3 * bf2f(bv[3].y)));
      ac.z = ac.z * scl + ((w0 * bf2f(bv[0].z) + w1 * bf2f(bv[1].z)) +
                           (w2 * bf2f(bv[2].z) + w3 * bf2f(bv[3].z)));
      ac.w = ac.w * scl + ((w0 * bf2f(bv[0].w) + w1 * bf2f(bv[1].w)) +
                           (w2 * bf2f(bv[2].w) + w3 * bf2f(bv[3].w)));
      wa = wa * scl + ((w0 * eat[0] + w1 * eat[1]) + (w2 * eat[2] + w3 * eat[3]));
    };

    // depth-3 rotation: two groups always in flight
    ld4(kA, vA, eatA, 0);
    ld4(kB, vB, eatB, 4);
    for (int g4 = 0; g4 < cnt; g4 += 12) {
      ld4(kC, vC, eatC, g4 + 8);
      proc4(kA, vA, eatA, g4);
      if (g4 + 4 >= cnt) break;
      ld4(kA, vA, eatA, g4 + 12);
      proc4(kB, vB, eatB, g4 + 4);
      if (g4 + 8 >= cnt) break;
      ld4(kB, vB, eatB, g4 + 16);
      proc4(kC, vC, eatC, g4 + 8);
    }
  }

  // epilogue
  float4 o = make_float4(0.f, 0.f, 0.f, 0.f);
  float wacc = 0.f;
  if (end > beg) {
    float inv = 1.0f / dn;
    o.x = ac.x * inv + be4.x;
    o.y = ac.y * inv + be4.y;
    o.z = ac.z * inv + be4.z;
    o.w = ac.w * inv + be4.w;
    wacc = wa * inv;
  }
  int lanebase = lane & 48;
#pragma unroll
  for (int tt = 0; tt < 16; ++tt) {
    float4 w4 = *(const float4*)(We_l + tt * 256 + 4 * lane);
    float wv = __shfl(wacc, lanebase + tt, 64);
    o.x += wv * w4.x; o.y += wv * w4.y; o.z += wv * w4.z; o.w += wv * w4.w;
  }

  // fused beta-gate blend
  ushort4 rh = *(const ushort4*)(Sp + (size_t)n * 256 + 4 * lane);
  float4 r = make_float4(bf2f(rh.x), bf2f(rh.y), bf2f(rh.z), bf2f(rh.w));
  int c = 4 * lane;
  float z = o.x * sWb[c] + o.y * sWb[c + 1] + o.z * sWb[c + 2] + o.w * sWb[c + 3]
          + r.x * sWb[256 + c] + r.y * sWb[257 + c] + r.z * sWb[258 + c] + r.w * sWb[259 + c]
          + (o.x - r.x) * sWb[512 + c] + (o.y - r.y) * sWb[513 + c]
          + (o.z - r.z) * sWb[514 + c] + (o.w - r.w) * sWb[515 + c];
#pragma unroll
  for (int off = 1; off < 64; off <<= 1) z += __shfl_xor(z, off, 64);
  float beta = 1.0f / (1.0f + __expf(-z));
  ushort4 xh;
  xh.x = f2bf(beta * r.x + (1.f - beta) * o.x);
  xh.y = f2bf(beta * r.y + (1.f - beta) * o.y);
  xh.z = f2bf(beta * r.z + (1.f - beta) * o.z);
  xh.w = f2bf(beta * r.w + (1.f - beta) * o.w);
  *(ushort4*)(xout + (size_t)n * 256 + 4 * lane) = xh;
}

// ---------------- batchnorm (bf16 x) ---------------------------------------
__global__ void k_bnstats(const ushort_t* __restrict__ x16, float* __restrict__ sums,
                          float* __restrict__ sums2, int nRows) {
  int c = threadIdx.x;
  int rpb = (nRows + gridDim.x - 1) / gridDim.x;
  int r0 = blockIdx.x * rpb;
  int r1 = min(nRows, r0 + rpb);
  float s = 0.f, s2 = 0.f;
  for (int r = r0; r < r1; ++r) {
    float v = bf2f(x16[(size_t)r * 256 + c]);
    s += v;
    s2 += v * v;
  }
  atomicAdd(&sums[c], s);
  atomicAdd(&sums2[c], s2);
}

__global__ __launch_bounds__(256) void k_bnapply16(
    ushort_t* __restrict__ x16, const float* __restrict__ sums,
    const float* __restrict__ sums2, const float* __restrict__ gamma,
    const float* __restrict__ betap, int nRows) {
  int total4 = nRows * 64;
  float invN = 1.0f / (float)nRows;
  for (int i4 = blockIdx.x * 256 + threadIdx.x; i4 < total4; i4 += gridDim.x * 256) {
    int c4 = (i4 & 63) * 4;
    ushort4 xh = *(const ushort4*)(x16 + (size_t)i4 * 4);
    float4 s = *(const float4*)(sums + c4);
    float4 s2 = *(const float4*)(sums2 + c4);
    float4 g = *(const float4*)(gamma + c4);
    float4 b = *(const float4*)(betap + c4);
    float mu0 = s.x * invN, mu1 = s.y * invN, mu2 = s.z * invN, mu3 = s.w * invN;
    float sc0 = rsqrtf(s2.x * invN - mu0 * mu0 + EPS) * g.x;
    float sc1 = rsqrtf(s2.y * invN - mu1 * mu1 + EPS) * g.y;
    float sc2 = rsqrtf(s2.z * invN - mu2 * mu2 + EPS) * g.z;
    float sc3 = rsqrtf(s2.w * invN - mu3 * mu3 + EPS) * g.w;
    float v0 = (bf2f(xh.x) - mu0) * sc0 + b.x;
    float v1 = (bf2f(xh.y) - mu1) * sc1 + b.y;
    float v2 = (bf2f(xh.z) - mu2) * sc2 + b.z;
    float v3 = (bf2f(xh.w) - mu3) * sc3 + b.w;
    v0 = v0 >= 0.f ? v0 : 0.1f * v0;
    v1 = v1 >= 0.f ? v1 : 0.1f * v1;
    v2 = v2 >= 0.f ? v2 : 0.1f * v2;
    v3 = v3 >= 0.f ? v3 : 0.1f * v3;
    ushort4 h;
    h.x = f2bf(v0); h.y = f2bf(v1); h.z = f2bf(v2); h.w = f2bf(v3);
    *(ushort4*)(x16 + (size_t)i4 * 4) = h;
  }
}

// ---------------- pooling (with fused final BN+LeakyReLU) + head -----------
__global__ void k_poolbn(const ushort_t* __restrict__ x16, const int* __restrict__ batch,
                         const float* __restrict__ sums, const float* __restrict__ sums2,
                         const float* __restrict__ gamma, const float* __restrict__ betap,
                         float* __restrict__ pool, int nRows) {
  int c = threadIdx.x;
  float invN = 1.0f / (float)nRows;
  float mu = sums[c] * invN;
  float var = sums2[c] * invN - mu * mu;
  float sc = rsqrtf(var + EPS) * gamma[c];
  float sh = betap[c] - mu * sc;
  int rpb = (nRows + gridDim.x - 1) / gridDim.x;
  int r0 = blockIdx.x * rpb;
  int r1 = min(nRows, r0 + rpb);
  float acc = 0.f;
  int gc = -1;
  for (int r = r0; r < r1; ++r) {
    int g = batch[r];
    if (g != gc) {
      if (gc >= 0) atomicAdd(&pool[gc * 256 + c], acc);
      acc = 0.f;
      gc = g;
    }
    float v = bf2f(x16[(size_t)r * 256 + c]) * sc + sh;
    v = v >= 0.f ? v : 0.1f * v;
    acc += v;
  }
  if (gc >= 0) atomicAdd(&pool[gc * 256 + c], acc);
}

// head with inline per-graph counts (batch sorted -> binary search)
__global__ void k_head(const float* __restrict__ pool, const int* __restrict__ batch,
                       const float* __restrict__ hW, const float* __restrict__ hb,
                       float* __restrict__ outp, int nRows) {
  int g = blockIdx.x, lane = threadIdx.x;
  int lo = 0, hi = nRows;
  while (lo < hi) { int mid = (lo + hi) >> 1; if (batch[mid] < g) lo = mid + 1; else hi = mid; }
  int lb = lo;
  lo = 0; hi = nRows;
  while (lo < hi) { int mid = (lo + hi) >> 1; if (batch[mid] < g + 1) lo = mid + 1; else hi = mid; }
  float cnt = fmaxf((float)(lo - lb), 1.0f);
  float z = 0.f;
#pragma unroll
  for (int i = 0; i < 4; ++i) {
    int c = lane + i * 64;
    float s = pool[g * 256 + c];
    z += (s / cnt) * hW[c] + s * hW[256 + c];
  }
#pragma unroll
  for (int off = 1; off < 64; off <<= 1) z += __shfl_xor(z, off, 64);
  if (lane == 0) outp[g] = z + hb[0];
}

// ---------------------------------------------------------------------------
extern "C" void kernel_launch(void* const* d_in, const int* in_sizes, int n_in,
                              void* d_out, int out_size, void* d_ws, size_t ws_size,
                              hipStream_t stream) {
  const float* node_features = (const float*)d_in[0];
  const int*   edge_index    = (const int*)d_in[1];
  const float* edge_attr     = (const float*)d_in[2];
  const int*   batch         = (const int*)d_in[3];
  const float* proj_W  = (const float*)d_in[4];
  const float* proj_b  = (const float*)d_in[5];
  const float* Wq      = (const float*)d_in[6];
  const float* bq      = (const float*)d_in[7];
  const float* Wk      = (const float*)d_in[8];
  const float* bk      = (const float*)d_in[9];
  const float* Wv      = (const float*)d_in[10];
  const float* bv      = (const float*)d_in[11];
  const float* We      = (const float*)d_in[12];
  const float* be      = (const float*)d_in[13];
  const float* Wskip   = (const float*)d_in[14];
  const float* bskip   = (const float*)d_in[15];
  const float* Wbeta   = (const float*)d_in[16];
  const float* bn_gamma= (const float*)d_in[17];
  const float* bn_beta = (const float*)d_in[18];
  const float* head_W  = (const float*)d_in[19];
  const float* head_b  = (const float*)d_in[20];
  float* out_dev = (float*)d_out;

  const int Nn = in_sizes[0] / 64;   // 50000
  const int Ee = in_sizes[1] / 2;    // 500000
  const int Gg = out_size;           // 64

  char* ws = (char*)d_ws;
  size_t off = 0;
  auto alloc = [&](size_t bytes) -> void* {
    void* p = ws + off;
    off += (bytes + 255) & ~(size_t)255;
    return p;
  };
  ushort_t* Dqb16  = (ushort_t*)alloc((size_t)Nn * 128 * 2);
  ushort_t* xb16   = (ushort_t*)alloc((size_t)Nn * 256 * 2);
  ushort_t* Qb16   = (ushort_t*)alloc((size_t)Nn * 256 * 2);
  ushort_t* Sb16   = (ushort_t*)alloc((size_t)Nn * 256 * 2);
  ushort_t* KVb    = (ushort_t*)alloc((size_t)Nn * 512 * 2);   // K plane | V plane
  ushort_t* Wcat_t = (ushort_t*)alloc((size_t)4 * 1152 * 256 * 2);
  float*    bias_cat = (float*)alloc((size_t)4 * 1152 * 4);
  float*    bnstat = (float*)alloc(512 * 4);
  float*    pool   = (float*)alloc((size_t)Gg * 256 * 4);
  int* deg     = (int*)alloc((size_t)Nn * 4);
  int* fill    = (int*)alloc((size_t)Nn * 4);
  int* row_ptr = (int*)alloc((size_t)(Nn + 1) * 4);
  int* csr     = (int*)alloc((size_t)Ee * 4);
  (void)ws_size; (void)n_in;

  const int* srcA = edge_index;
  const int* dstA = edge_index + Ee;

  // CSR build by dst
  hipMemsetAsync(deg, 0, (size_t)Nn * 4, stream);
  hipMemsetAsync(fill, 0, (size_t)Nn * 4, stream);
  k_count<<<(Ee + 255) / 256, 256, 0, stream>>>(dstA, deg, Ee);
  k_scan<<<1, 1024, 0, stream>>>(deg, row_ptr, Nn);
  k_scatter<<<(Ee + 255) / 256, 256, 0, stream>>>(dstA, row_ptr, fill, csr, Ee);

  // weight/bias conversion (bf16, transposed concat) + composite dq rows
  k_wconv<<<dim3(8, 8, 16), dim3(32, 8), 0, stream>>>(Wq, Wk, Wv, Wskip, Wcat_t);
  k_bconv<<<16, 256, 0, stream>>>(bq, bk, bv, bskip, bias_cat);
  k_mkdq<<<dim3(68, 4), 256, 0, stream>>>(Wq, bq, We, be, Wcat_t, bias_cat);

  // input projection (fp32 -> bf16)
  dim3 gemm_grid(256 / BN, (Nn + BM - 1) / BM);
  k_gemm<<<gemm_grid, 256, 0, stream>>>(node_features, proj_W, proj_b, xb16, Nn, 64, 256);

  int nodeBlocks = (Nn + 3) / 4;
  dim3 qkvs_grid(9, (Nn + 127) / 128);
  for (int l = 0; l < 4; ++l) {
    k_qkvs<<<qkvs_grid, 256, 0, stream>>>(xb16, Wcat_t + (size_t)l * (1152 * 256),
                                          bias_cat + l * 1152, Qb16, KVb, Sb16, Dqb16, Nn);

    k_attn<<<nodeBlocks, 256, 0, stream>>>(Qb16, KVb, Dqb16, edge_attr, srcA,
                                           We + (size_t)l * 4096, be + l * 256,
                                           Wbeta + (size_t)l * 768,
                                           row_ptr, csr, Sb16, xb16, Nn);

    hipMemsetAsync(bnstat, 0, 512 * 4, stream);
    k_bnstats<<<512, 256, 0, stream>>>(xb16, bnstat, bnstat + 256, Nn);
    if (l < 3) {
      k_bnapply16<<<512, 256, 0, stream>>>(xb16, bnstat, bnstat + 256,
                                           bn_gamma + l * 256, bn_beta + l * 256, Nn);
    }
  }

  // final BN+LeakyReLU fused into pooling
  hipMemsetAsync(pool, 0, (size_t)Gg * 256 * 4, stream);
  k_poolbn<<<256, 256, 0, stream>>>(xb16, batch, bnstat, bnstat + 256,
                                    bn_gamma + 3 * 256, bn_beta + 3 * 256, pool, Nn);
  k_head<<<Gg, 64, 0, stream>>>(pool, batch, head_W, head_b, out_dev, Nn);
}